// Round 5
// baseline (362.725 us; speedup 1.0000x reference)
//
#include <hip/hip_runtime.h>
#include <math.h>

#define L_DIM 2048
#define S_DIM 2048
#define E_DIM 2048
#define H_DIM 16
#define D_HEAD 128

using bf16x8 = __attribute__((ext_vector_type(8))) short;  // 8 bf16 in 4 VGPRs
using f32x4  = __attribute__((ext_vector_type(4))) float;  // MFMA C/D frag

// Pack two fp32 -> two bf16 (round-half-up) in one v_perm after two adds.
__device__ __forceinline__ unsigned pack2_bf16(float a, float b) {
  unsigned ua = __builtin_bit_cast(unsigned, a) + 0x8000u;
  unsigned ub = __builtin_bit_cast(unsigned, b) + 0x8000u;
  return __builtin_amdgcn_perm(ub, ua, 0x07060302u);
}
__device__ __forceinline__ unsigned short f2bf(float a) {
  unsigned u = __builtin_bit_cast(unsigned, a) + 0x8000u;
  return (unsigned short)(u >> 16);
}
__device__ __forceinline__ float bflo(unsigned u) {
  return __builtin_bit_cast(float, u << 16);
}
__device__ __forceinline__ float bfhi(unsigned u) {
  return __builtin_bit_cast(float, u & 0xffff0000u);
}

// async global->LDS, 16B per lane. LDS dst is wave-uniform base + lane*16.
__device__ __forceinline__ void gl_lds16(const unsigned short* g, unsigned short* l) {
  __builtin_amdgcn_global_load_lds(
      (const __attribute__((address_space(1))) void*)g,
      (__attribute__((address_space(3))) void*)l, 16, 0, 0);
}

#define FA_SFT 23.083120654223414f   // 16 * log2(e): fixed softmax shift
#define FA_C1  0.12752977f           // (1/sqrt(128)) * log2(e)

// ---------------------------------------------------------------------------
// fp32 -> bf16 conversion (z=0..6, 7 slices of E*E) + time_bias (z=7).
// time_bias[h][s] = (dot(time_emb[s,:], tp_w[h,:]) + tp_b[h])*log2e - FA_SFT
// ---------------------------------------------------------------------------
__global__ __launch_bounds__(256)
void convert_bf16(const float* __restrict__ q, const float* __restrict__ k,
                  const float* __restrict__ v, const float* __restrict__ w_in,
                  const float* __restrict__ w_out,
                  unsigned short* __restrict__ qa, unsigned short* __restrict__ ka,
                  unsigned short* __restrict__ va, unsigned short* __restrict__ wqkv,
                  unsigned short* __restrict__ wo,
                  const float* __restrict__ temb, const float* __restrict__ tpw,
                  const float* __restrict__ tpb, float* __restrict__ tb)
{
  const int z = blockIdx.y;
  if (z == 7) {      // time_bias: 512 blocks x 4 waves, one wave per s
    if (blockIdx.x >= 512) return;
    const int lane = threadIdx.x & 63;
    const int wave = threadIdx.x >> 6;
    const int s = blockIdx.x * 4 + wave;
    float acc[16];
#pragma unroll
    for (int hh = 0; hh < 16; hh++) acc[hh] = 0.f;
    for (int i = 0; i < 32; i++) {
      int e = lane + i * 64;
      float t = temb[(size_t)s * E_DIM + e];
#pragma unroll
      for (int hh = 0; hh < 16; hh++)
        acc[hh] = fmaf(t, tpw[hh * E_DIM + e], acc[hh]);
    }
#pragma unroll
    for (int hh = 0; hh < 16; hh++) {
#pragma unroll
      for (int d = 1; d < 64; d <<= 1)
        acc[hh] += __shfl_xor(acc[hh], d, 64);
    }
#pragma unroll
    for (int hh = 0; hh < 16; hh++)
      if (lane == hh)
        tb[(size_t)hh * S_DIM + s] = (acc[hh] + tpb[hh]) * 1.44269504f - FA_SFT;
    return;
  }
  const float* src;
  unsigned short* dst;
  switch (z) {
    case 0: src = q; dst = qa; break;
    case 1: src = k; dst = ka; break;
    case 2: src = v; dst = va; break;
    case 3: src = w_in;           dst = wqkv;           break;
    case 4: src = w_in + 4194304; dst = wqkv + 4194304; break;
    case 5: src = w_in + 8388608; dst = wqkv + 8388608; break;
    default: src = w_out; dst = wo; break;
  }
  size_t i = ((size_t)blockIdx.x * 256 + threadIdx.x) * 8;
  float4 a = *(const float4*)(src + i);
  float4 b = *(const float4*)(src + i + 4);
  uint4 o;
  o.x = pack2_bf16(a.x, a.y);
  o.y = pack2_bf16(a.z, a.w);
  o.z = pack2_bf16(b.x, b.y);
  o.w = pack2_bf16(b.z, b.w);
  *(uint4*)(dst + i) = o;
}

// ---------------------------------------------------------------------------
// bf16 GEMM-NT, m97-style, GBK=64 (half the barrier drains of GBK=32).
// LDS layout: 8 groups of 16 rows; within a group, chunk(row m, 16B-col c)
// lives at slot 8m + (c ^ (m&7)). Staging lane i of DMA window j writes
// slot 64j+i (contiguous); frag reads are a 64-slot permutation per step
// with 8 lanes per 4-bank group -> conflict-free.
// MODE 0: QKV projection (z = q/k/v, z=2 writes V^T).
// MODE 1: out-projection, split-K x2 over z (z=0 adds bias+residual).
// ---------------------------------------------------------------------------
#define GBM 128
#define GBN 128
#define GBK 64

template<int MODE>
__global__ __launch_bounds__(256, 2)
void gemm_bt(const unsigned short* __restrict__ Aq, const unsigned short* __restrict__ Ak,
             const unsigned short* __restrict__ Av, const unsigned short* __restrict__ Bmat,
             const float* __restrict__ bias0,
             unsigned short* __restrict__ qb, unsigned short* __restrict__ kb,
             unsigned short* __restrict__ vt,
             const float* __restrict__ Res, float* __restrict__ Xout,
             float* __restrict__ Xout2)
{
  __shared__ unsigned short As[GBM * GBK];   // 16 KB, swizzled
  __shared__ unsigned short Bs[GBN * GBK];   // 16 KB, swizzled
  const int tid  = threadIdx.x;
  const int lane = tid & 63;
  const int wave = tid >> 6;
  const int quad = lane >> 4;
  const int c16  = lane & 15;
  const int m0 = blockIdx.y * GBM;
  const int n0 = blockIdx.x * GBN;
  const int z  = blockIdx.z;

  const unsigned short* A;
  const unsigned short* B;
  const float* bias;
  int kbeg, kend;
  if (MODE == 0) {
    A = (z == 0) ? Aq : (z == 1) ? Ak : Av;
    B = Bmat + (size_t)z * E_DIM * E_DIM;
    bias = bias0 + z * E_DIM;
    kbeg = 0; kend = E_DIM;
  } else {
    A = Aq; B = Bmat; bias = bias0;
    kbeg = z * 1024; kend = kbeg + 1024;
  }

  // staging: wave handles groups {wave, wave+4} of A and B; 2 DMA windows
  // (j=0,1) per group. lane i -> row j*8 + (i>>3), col chunk (i&7)^(i>>3).
  const int srow = lane >> 3;              // 0..7
  const int sc   = (lane & 7) ^ srow;      // XOR-swizzled 16B chunk
  const unsigned short* aG00 = A + (size_t)(m0 + wave * 16 + srow) * E_DIM + kbeg + sc * 8;
  const unsigned short* aG01 = aG00 + (size_t)8 * E_DIM;
  const unsigned short* aG10 = aG00 + (size_t)64 * E_DIM;
  const unsigned short* aG11 = aG00 + (size_t)72 * E_DIM;
  const unsigned short* bG00 = B + (size_t)(n0 + wave * 16 + srow) * E_DIM + kbeg + sc * 8;
  const unsigned short* bG01 = bG00 + (size_t)8 * E_DIM;
  const unsigned short* bG10 = bG00 + (size_t)64 * E_DIM;
  const unsigned short* bG11 = bG00 + (size_t)72 * E_DIM;
  unsigned short* aS00 = &As[wave * 1024];
  unsigned short* aS01 = aS00 + 512;
  unsigned short* aS10 = &As[(wave + 4) * 1024];
  unsigned short* aS11 = aS10 + 512;
  unsigned short* bS00 = &Bs[wave * 1024];
  unsigned short* bS01 = bS00 + 512;
  unsigned short* bS10 = &Bs[(wave + 4) * 1024];
  unsigned short* bS11 = bS10 + 512;

  // frag-read slot offsets (shorts): step s, tile row m=c16, chunk s*4+quad
  const int k7 = c16 & 7;
  const int fr0 = (8 * c16 + ((0 * 4 + quad) ^ k7)) * 8;
  const int fr1 = (8 * c16 + ((1 * 4 + quad) ^ k7)) * 8;

  f32x4 acc[4][4];
#pragma unroll
  for (int i = 0; i < 4; i++)
#pragma unroll
    for (int j = 0; j < 4; j++) acc[i][j] = (f32x4){0.f, 0.f, 0.f, 0.f};

  const int wm = (wave >> 1) * 64;
  const int wn = (wave & 1) * 64;
  const int ga = (wm >> 4);
  const int gb = (wn >> 4);

  for (int k0 = kbeg; k0 < kend; k0 += GBK) {
    __syncthreads();
    gl_lds16(aG00, aS00); gl_lds16(aG01, aS01);
    gl_lds16(aG10, aS10); gl_lds16(aG11, aS11);
    gl_lds16(bG00, bS00); gl_lds16(bG01, bS01);
    gl_lds16(bG10, bS10); gl_lds16(bG11, bS11);
    aG00 += GBK; aG01 += GBK; aG10 += GBK; aG11 += GBK;
    bG00 += GBK; bG01 += GBK; bG10 += GBK; bG11 += GBK;
    __syncthreads();

#pragma unroll
    for (int s = 0; s < 2; s++) {
      const int fr = s ? fr1 : fr0;
      bf16x8 af[4], bfr[4];
#pragma unroll
      for (int t = 0; t < 4; t++) {
        af[t]  = *(const bf16x8*)&As[(ga + t) * 1024 + fr];
        bfr[t] = *(const bf16x8*)&Bs[(gb + t) * 1024 + fr];
      }
#pragma unroll
      for (int tm = 0; tm < 4; tm++)
#pragma unroll
        for (int tn = 0; tn < 4; tn++)
          acc[tm][tn] = __builtin_amdgcn_mfma_f32_16x16x32_bf16(af[tm], bfr[tn],
                                                                acc[tm][tn], 0, 0, 0);
    }
  }

  float bv[4];
#pragma unroll
  for (int tn = 0; tn < 4; tn++) bv[tn] = bias[n0 + wn + tn * 16 + c16];

  if (MODE == 1) {
    if (z == 0) {
#pragma unroll
      for (int tm = 0; tm < 4; tm++) {
        int mr = m0 + wm + tm * 16 + quad * 4;
#pragma unroll
        for (int tn = 0; tn < 4; tn++) {
          int n = n0 + wn + tn * 16 + c16;
#pragma unroll
          for (int r = 0; r < 4; r++) {
            size_t idx = (size_t)(mr + r) * E_DIM + n;
            Xout[idx] = acc[tm][tn][r] + bv[tn] + Res[idx];
          }
        }
      }
    } else {
#pragma unroll
      for (int tm = 0; tm < 4; tm++) {
        int mr = m0 + wm + tm * 16 + quad * 4;
#pragma unroll
        for (int tn = 0; tn < 4; tn++) {
          int n = n0 + wn + tn * 16 + c16;
#pragma unroll
          for (int r = 0; r < 4; r++)
            Xout2[(size_t)(mr + r) * E_DIM + n] = acc[tm][tn][r];
        }
      }
    }
  } else if (z < 2) {
    unsigned short* O = (z == 0) ? qb : kb;
#pragma unroll
    for (int tm = 0; tm < 4; tm++) {
      int mr = m0 + wm + tm * 16 + quad * 4;
#pragma unroll
      for (int tn = 0; tn < 4; tn++) {
        int n = n0 + wn + tn * 16 + c16;
#pragma unroll
        for (int r = 0; r < 4; r++)
          O[(size_t)(mr + r) * E_DIM + n] = f2bf(acc[tm][tn][r] + bv[tn]);
      }
    }
  } else {
#pragma unroll
    for (int tm = 0; tm < 4; tm++) {
      int mr = m0 + wm + tm * 16 + quad * 4;
#pragma unroll
      for (int tn = 0; tn < 4; tn++) {
        int n = n0 + wn + tn * 16 + c16;
        uint2 pv;
        pv.x = pack2_bf16(acc[tm][tn][0] + bv[tn], acc[tm][tn][1] + bv[tn]);
        pv.y = pack2_bf16(acc[tm][tn][2] + bv[tn], acc[tm][tn][3] + bv[tn]);
        *(uint2*)(vt + (size_t)n * S_DIM + mr) = pv;
      }
    }
  }
}

// ---------------------------------------------------------------------------
// Flash attention v4 (unchanged from R4: prefetch after barrier B, operand-
// swapped QK, fixed-max softmax, split-S x2, 40 KB LDS -> 4 blocks/CU).
// ---------------------------------------------------------------------------
__global__ __launch_bounds__(256, 4)
void flash_attn(const unsigned short* __restrict__ qb,
                const unsigned short* __restrict__ kb,
                const unsigned short* __restrict__ vt,
                const float* __restrict__ tb,
                unsigned short* __restrict__ Opart,
                float* __restrict__ lsum)
{
  __shared__ unsigned short Ks[64 * 128];   // 16 KB, swizzled
  __shared__ unsigned short Vs[128 * 64];   // 16 KB, swizzled (V^T)
  __shared__ unsigned short Ps[64 * 64];    //  8 KB, swizzled

  const int tid  = threadIdx.x;
  const int lane = tid & 63;
  const int wave = tid >> 6;
  const int quad = lane >> 4;
  const int c16  = lane & 15;
  const int h     = blockIdx.y;
  const int z     = blockIdx.z;
  const int lrow0 = blockIdx.x * 64 + wave * 16;
  const int sbase = z * 1024;

  bf16x8 qf[4];
#pragma unroll
  for (int kd = 0; kd < 4; kd++)
    qf[kd] = *(const bf16x8*)(qb + (size_t)(lrow0 + c16) * E_DIM + h * D_HEAD
                              + kd * 32 + quad * 8);

  const int krow = tid >> 4;
  const int kc   = tid & 15;
  const int vrow = tid >> 3;
  const int vc   = tid & 7;
  const unsigned short* kg = kb + (size_t)(sbase + krow) * E_DIM + h * D_HEAD + kc * 8;
  const unsigned short* vg = vt + (size_t)(h * D_HEAD + vrow) * S_DIM + sbase + vc * 8;
  const int kslot = (kc ^ krow) * 8;
  const int vslot = (vc ^ (vrow & 7)) * 8;
  const float* tbh = tb + (size_t)h * S_DIM + sbase;

  f32x4 of[8];
#pragma unroll
  for (int i = 0; i < 8; i++) of[i] = (f32x4){0.f, 0.f, 0.f, 0.f};
  float li4[4] = {0.f, 0.f, 0.f, 0.f};

  bf16x8 kreg[4], vreg[4];
#pragma unroll
  for (int i = 0; i < 4; i++) kreg[i] = *(const bf16x8*)(kg + (size_t)i * 16 * E_DIM);
#pragma unroll
  for (int i = 0; i < 4; i++) vreg[i] = *(const bf16x8*)(vg + (size_t)i * 32 * S_DIM);

  const int prow = (wave * 16 + c16) * 64;
  const int k7   = c16 & 7;

  for (int ch = 0; ch < 16; ch++) {
    __syncthreads();   // A: drains prefetch (issued a full compute phase ago)
#pragma unroll
    for (int i = 0; i < 4; i++)
      *(bf16x8*)&Ks[(krow + 16 * i) * 128 + kslot] = kreg[i];
#pragma unroll
    for (int i = 0; i < 4; i++)
      *(bf16x8*)&Vs[(vrow + 32 * i) * 64 + vslot] = vreg[i];
    __syncthreads();   // B: vmcnt already 0 -> cheap

    if (ch < 15) {     // prefetch next chunk: stays in flight through compute
      const unsigned short* kg2 = kg + (size_t)(ch + 1) * 64 * E_DIM;
      const unsigned short* vg2 = vg + (ch + 1) * 64;
#pragma unroll
      for (int i = 0; i < 4; i++) kreg[i] = *(const bf16x8*)(kg2 + (size_t)i * 16 * E_DIM);
#pragma unroll
      for (int i = 0; i < 4; i++) vreg[i] = *(const bf16x8*)(vg2 + (size_t)i * 32 * S_DIM);
    }

    float4 bb[4];
#pragma unroll
    for (int tn = 0; tn < 4; tn++)
      bb[tn] = *(const float4*)(tbh + ch * 64 + tn * 16 + quad * 4);

    // S^T = K * Q^T: sc[tn][r] = S[l=c16][s = tn*16 + quad*4 + r]
    f32x4 sc[4];
#pragma unroll
    for (int tn = 0; tn < 4; tn++) sc[tn] = (f32x4){0.f, 0.f, 0.f, 0.f};
#pragma unroll
    for (int tn = 0; tn < 4; tn++)
#pragma unroll
      for (int kd = 0; kd < 4; kd++) {
        bf16x8 kf = *(const bf16x8*)&Ks[(tn * 16 + c16) * 128
                                        + (((kd * 4 + quad) ^ c16) << 3)];
        sc[tn] = __builtin_amdgcn_mfma_f32_16x16x32_bf16(kf, qf[kd], sc[tn], 0, 0, 0);
      }

#pragma unroll
    for (int tn = 0; tn < 4; tn++) {
      float p0 = exp2f(fmaf(sc[tn][0], FA_C1, bb[tn].x));
      float p1 = exp2f(fmaf(sc[tn][1], FA_C1, bb[tn].y));
      float p2 = exp2f(fmaf(sc[tn][2], FA_C1, bb[tn].z));
      float p3 = exp2f(fmaf(sc[tn][3], FA_C1, bb[tn].w));
      li4[tn] += (p0 + p1) + (p2 + p3);
      uint2 pv;
      pv.x = pack2_bf16(p0, p1);
      pv.y = pack2_bf16(p2, p3);
      int p8 = (((tn * 2 + (quad >> 1)) ^ k7) << 1) | (quad & 1);
      *(uint2*)&Ps[prow + p8 * 4] = pv;
    }

#pragma unroll
    for (int ks = 0; ks < 2; ks++) {
      int po = ((ks * 4 + quad) ^ k7) << 3;
      bf16x8 ap = *(const bf16x8*)&Ps[prow + po];
#pragma unroll
      for (int td = 0; td < 8; td++) {
        bf16x8 vf = *(const bf16x8*)&Vs[(td * 16 + c16) * 64 + po];
        of[td] = __builtin_amdgcn_mfma_f32_16x16x32_bf16(ap, vf, of[td], 0, 0, 0);
      }
    }
  }

  float lt = (li4[0] + li4[1]) + (li4[2] + li4[3]);
  lt += __shfl_xor(lt, 16, 64);
  lt += __shfl_xor(lt, 32, 64);
  if (quad == 0)
    lsum[(size_t)z * 32768 + (size_t)h * 2048 + lrow0 + c16] = lt;

#pragma unroll
  for (int r = 0; r < 4; r++) {
    size_t lrow = lrow0 + quad * 4 + r;
#pragma unroll
    for (int td = 0; td < 8; td++)
      Opart[((size_t)z * 2048 + lrow) * 2048 + h * D_HEAD + td * 16 + c16] =
          f2bf(of[td][r]);
  }
}

// ---------------------------------------------------------------------------
// combine: ctx = (O0 + O1) / (l0 + l1), bf16 in/out.
// ---------------------------------------------------------------------------
__global__ __launch_bounds__(256)
void combine_kernel(const unsigned short* __restrict__ Opart,
                    const float* __restrict__ lsum,
                    unsigned short* __restrict__ ctx)
{
  size_t i = ((size_t)blockIdx.x * 256 + threadIdx.x) * 8;
  int l = (int)(i >> 11);
  int e = (int)(i & 2047);
  int h = e >> 7;
  float inv = 1.0f / (lsum[h * 2048 + l] + lsum[32768 + h * 2048 + l]);
  uint4 a = *(const uint4*)(Opart + i);
  uint4 b = *(const uint4*)(Opart + 4194304 + i);
  uint4 o;
  o.x = pack2_bf16((bflo(a.x) + bflo(b.x)) * inv, (bfhi(a.x) + bfhi(b.x)) * inv);
  o.y = pack2_bf16((bflo(a.y) + bflo(b.y)) * inv, (bfhi(a.y) + bfhi(b.y)) * inv);
  o.z = pack2_bf16((bflo(a.z) + bflo(b.z)) * inv, (bfhi(a.z) + bfhi(b.z)) * inv);
  o.w = pack2_bf16((bflo(a.w) + bflo(b.w)) * inv, (bfhi(a.w) + bfhi(b.w)) * inv);
  *(uint4*)(ctx + i) = o;
}

// ---------------------------------------------------------------------------
// LayerNorm over rows of (xb0 + xb1) (split-K partials), eps=1e-5
// ---------------------------------------------------------------------------
__global__ __launch_bounds__(256)
void layernorm_kernel(const float* __restrict__ x0, const float* __restrict__ x1,
                      const float* __restrict__ g, const float* __restrict__ b,
                      float* __restrict__ out)
{
  const int row = blockIdx.x;
  const int tid = threadIdx.x;
  const int lane = tid & 63, wave = tid >> 6;
  const float* xr0 = x0 + (size_t)row * E_DIM;
  const float* xr1 = x1 + (size_t)row * E_DIM;
  float4 a0 = *(const float4*)(xr0 + tid * 4);
  float4 a1 = *(const float4*)(xr0 + 1024 + tid * 4);
  float4 c0 = *(const float4*)(xr1 + tid * 4);
  float4 c1 = *(const float4*)(xr1 + 1024 + tid * 4);
  float4 v0 = {a0.x + c0.x, a0.y + c0.y, a0.z + c0.z, a0.w + c0.w};
  float4 v1 = {a1.x + c1.x, a1.y + c1.y, a1.z + c1.z, a1.w + c1.w};
  float s  = v0.x + v0.y + v0.z + v0.w + v1.x + v1.y + v1.z + v1.w;
  float ss = v0.x*v0.x + v0.y*v0.y + v0.z*v0.z + v0.w*v0.w
           + v1.x*v1.x + v1.y*v1.y + v1.z*v1.z + v1.w*v1.w;
#pragma unroll
  for (int d = 1; d < 64; d <<= 1) {
    s  += __shfl_xor(s, d, 64);
    ss += __shfl_xor(ss, d, 64);
  }
  __shared__ float red[8];
  if (lane == 0) { red[wave] = s; red[wave + 4] = ss; }
  __syncthreads();
  s  = red[0] + red[1] + red[2] + red[3];
  ss = red[4] + red[5] + red[6] + red[7];
  float mu   = s * (1.f / E_DIM);
  float var  = ss * (1.f / E_DIM) - mu * mu;
  float rstd = rsqrtf(var + 1e-5f);

  float4 g0 = *(const float4*)(g + tid * 4);
  float4 b0 = *(const float4*)(b + tid * 4);
  float4 g1 = *(const float4*)(g + 1024 + tid * 4);
  float4 b1 = *(const float4*)(b + 1024 + tid * 4);
  float4 o0, o1;
  o0.x = (v0.x - mu) * rstd * g0.x + b0.x;
  o0.y = (v0.y - mu) * rstd * g0.y + b0.y;
  o0.z = (v0.z - mu) * rstd * g0.z + b0.z;
  o0.w = (v0.w - mu) * rstd * g0.w + b0.w;
  o1.x = (v1.x - mu) * rstd * g1.x + b1.x;
  o1.y = (v1.y - mu) * rstd * g1.y + b1.y;
  o1.z = (v1.z - mu) * rstd * g1.z + b1.z;
  o1.w = (v1.w - mu) * rstd * g1.w + b1.w;
  *(float4*)(out + (size_t)row * E_DIM + tid * 4) = o0;
  *(float4*)(out + (size_t)row * E_DIM + 1024 + tid * 4) = o1;
}

extern "C" void kernel_launch(void* const* d_in, const int* in_sizes, int n_in,
                              void* d_out, int out_size, void* d_ws, size_t ws_size,
                              hipStream_t stream) {
  const float* query     = (const float*)d_in[0];
  const float* key       = (const float*)d_in[1];
  const float* value     = (const float*)d_in[2];
  const float* time_emb  = (const float*)d_in[3];
  const float* in_proj_w = (const float*)d_in[4];
  const float* in_proj_b = (const float*)d_in[5];
  const float* out_w     = (const float*)d_in[6];
  const float* out_b     = (const float*)d_in[7];
  const float* tp_w      = (const float*)d_in[8];
  const float* tp_b      = (const float*)d_in[9];
  const float* ln_g      = (const float*)d_in[10];
  const float* ln_b      = (const float*)d_in[11];

  char* ws = (char*)d_ws;
  unsigned short* qa   = (unsigned short*)(ws + 0);         //  8 MB (dead after gemm0)
  unsigned short* ka   = (unsigned short*)(ws + 8388608);   //  8 MB (dead after gemm0)
  unsigned short* va   = (unsigned short*)(ws + 16777216);  //  8 MB (dead after gemm0)
  unsigned short* wqkv = (unsigned short*)(ws + 25165824);  // 24 MB (dead after gemm0)
  unsigned short* wo   = (unsigned short*)(ws + 50331648);  //  8 MB (until gemm1)
  unsigned short* qb   = (unsigned short*)(ws + 58720256);  //  8 MB (until flash)
  unsigned short* kb   = (unsigned short*)(ws + 67108864);  //  8 MB (until flash)
  unsigned short* vt   = (unsigned short*)(ws + 75497472);  //  8 MB (until flash)
  float*          tb   = (float*)(ws + 83886080);           // 128 KB (until flash)
  // aliases (serial stream; lifetimes disjoint):
  unsigned short* Opart = (unsigned short*)(ws + 0);        // 16 MB over qa/ka (dead)
  float*          lsum  = (float*)(ws + 16777216);          // 256 KB over va (dead)
  unsigned short* ctx   = (unsigned short*)(ws + 33554432); //  8 MB over wqkv (dead)
  float*          xb0   = (float*)(ws + 0);                 // 16 MB over Opart (dead)
  float*          xb1   = (float*)(ws + 16777216);          // 16 MB over lsum (dead)

  // 1) fp32 -> bf16 conversions + time_bias (z=7)
  convert_bf16<<<dim3(2048, 8), 256, 0, stream>>>(query, key, value, in_proj_w,
                                                  out_w, qa, ka, va, wqkv, wo,
                                                  time_emb, tp_w, tp_b, tb);
  // 2) QKV projection (z selects q/k/v; V stored transposed)
  gemm_bt<0><<<dim3(16, 16, 3), 256, 0, stream>>>(qa, ka, va, wqkv, in_proj_b,
                                                  qb, kb, vt, nullptr, nullptr,
                                                  nullptr);
  // 3) flash attention, split-S x2 -> unnormalized bf16 partials
  flash_attn<<<dim3(32, 16, 2), 256, 0, stream>>>(qb, kb, vt, tb, Opart, lsum);
  // 4) combine partials -> ctx (bf16)
  combine_kernel<<<2048, 256, 0, stream>>>(Opart, lsum, ctx);
  // 5) out projection split-K x2 (+ bias + residual on z=0) -> xb0, xb1
  gemm_bt<1><<<dim3(16, 16, 2), 256, 0, stream>>>(ctx, nullptr, nullptr, wo,
                                                  out_b, nullptr, nullptr, nullptr,
                                                  query, xb0, xb1);
  // 6) LayerNorm over xb0+xb1 -> d_out
  layernorm_kernel<<<2048, 256, 0, stream>>>(xb0, xb1, ln_g, ln_b, (float*)d_out);
}

// Round 6
// 335.970 us; speedup vs baseline: 1.0796x; 1.0796x over previous
//
#include <hip/hip_runtime.h>
#include <math.h>

#define L_DIM 2048
#define S_DIM 2048
#define E_DIM 2048
#define H_DIM 16
#define D_HEAD 128

using bf16x8 = __attribute__((ext_vector_type(8))) short;  // 8 bf16 in 4 VGPRs
using f32x4  = __attribute__((ext_vector_type(4))) float;  // MFMA C/D frag

// Pack two fp32 -> two bf16 (round-half-up) in one v_perm after two adds.
__device__ __forceinline__ unsigned pack2_bf16(float a, float b) {
  unsigned ua = __builtin_bit_cast(unsigned, a) + 0x8000u;
  unsigned ub = __builtin_bit_cast(unsigned, b) + 0x8000u;
  return __builtin_amdgcn_perm(ub, ua, 0x07060302u);
}
__device__ __forceinline__ unsigned short f2bf(float a) {
  unsigned u = __builtin_bit_cast(unsigned, a) + 0x8000u;
  return (unsigned short)(u >> 16);
}
__device__ __forceinline__ float bflo(unsigned u) {
  return __builtin_bit_cast(float, u << 16);
}
__device__ __forceinline__ float bfhi(unsigned u) {
  return __builtin_bit_cast(float, u & 0xffff0000u);
}

// async global->LDS, 16B per lane. LDS dst is wave-uniform base + lane*16.
__device__ __forceinline__ void gl_lds16(const unsigned short* g, unsigned short* l) {
  __builtin_amdgcn_global_load_lds(
      (const __attribute__((address_space(1))) void*)g,
      (__attribute__((address_space(3))) void*)l, 16, 0, 0);
}

#define FA_SFT 23.083120654223414f   // 16 * log2(e): fixed softmax shift
#define FA_C1  0.12752977f           // (1/sqrt(128)) * log2(e)

// ---------------------------------------------------------------------------
// fp32 -> bf16 conversion. 7 slices of E*E; 512 blocks/slice; 32 elems/thread
// as 4 groups of 8 -> 8 INDEPENDENT float4 loads in flight per thread
// (R5's 2-load version was MLP-starved at 1.5 TB/s).
// ---------------------------------------------------------------------------
__global__ __launch_bounds__(256)
void convert_bf16(const float* __restrict__ q, const float* __restrict__ k,
                  const float* __restrict__ v, const float* __restrict__ w_in,
                  const float* __restrict__ w_out,
                  unsigned short* __restrict__ qa, unsigned short* __restrict__ ka,
                  unsigned short* __restrict__ va, unsigned short* __restrict__ wqkv,
                  unsigned short* __restrict__ wo)
{
  const int slice = blockIdx.x >> 9;         // 512 blocks per E*E slice
  const int sb    = blockIdx.x & 511;
  const float* src;
  unsigned short* dst;
  switch (slice) {
    case 0: src = q; dst = qa; break;
    case 1: src = k; dst = ka; break;
    case 2: src = v; dst = va; break;
    case 3: src = w_in;           dst = wqkv;           break;
    case 4: src = w_in + 4194304; dst = wqkv + 4194304; break;
    case 5: src = w_in + 8388608; dst = wqkv + 8388608; break;
    default: src = w_out; dst = wo; break;
  }
  const size_t base = (size_t)sb * 8192 + threadIdx.x * 8;
  float4 v8[8];
#pragma unroll
  for (int g = 0; g < 4; g++) {
    v8[2 * g]     = *(const float4*)(src + base + g * 2048);
    v8[2 * g + 1] = *(const float4*)(src + base + g * 2048 + 4);
  }
#pragma unroll
  for (int g = 0; g < 4; g++) {
    uint4 o;
    o.x = pack2_bf16(v8[2 * g].x,     v8[2 * g].y);
    o.y = pack2_bf16(v8[2 * g].z,     v8[2 * g].w);
    o.z = pack2_bf16(v8[2 * g + 1].x, v8[2 * g + 1].y);
    o.w = pack2_bf16(v8[2 * g + 1].z, v8[2 * g + 1].w);
    *(uint4*)(dst + base + g * 2048) = o;
  }
}

// ---------------------------------------------------------------------------
// time_bias[h][s] = (dot(time_emb[s,:], tp_w[h,:]) + tp_b[h])*log2e - FA_SFT
// (pre-scaled for flash exp2). One wave per s, standalone (R5's merge into
// convert added a latency tail to the big kernel).
// ---------------------------------------------------------------------------
__global__ __launch_bounds__(256)
void time_bias_kernel(const float* __restrict__ temb, const float* __restrict__ tpw,
                      const float* __restrict__ tpb, float* __restrict__ tb)
{
  const int lane = threadIdx.x & 63;
  const int wave = threadIdx.x >> 6;
  const int s = blockIdx.x * 4 + wave;
  float acc[16];
#pragma unroll
  for (int hh = 0; hh < 16; hh++) acc[hh] = 0.f;
  for (int i = 0; i < 32; i++) {
    int e = lane + i * 64;
    float t = temb[(size_t)s * E_DIM + e];
#pragma unroll
    for (int hh = 0; hh < 16; hh++)
      acc[hh] = fmaf(t, tpw[hh * E_DIM + e], acc[hh]);
  }
#pragma unroll
  for (int hh = 0; hh < 16; hh++) {
#pragma unroll
    for (int d = 1; d < 64; d <<= 1)
      acc[hh] += __shfl_xor(acc[hh], d, 64);
  }
#pragma unroll
  for (int hh = 0; hh < 16; hh++)
    if (lane == hh)
      tb[(size_t)hh * S_DIM + s] = (acc[hh] + tpb[hh]) * 1.44269504f - FA_SFT;
}

// ---------------------------------------------------------------------------
// bf16 GEMM-NT, m97-style, GBK=64. LDS: 8 groups of 16 rows; chunk(row m,
// 16B-col c) at slot 8m + (c ^ (m&7)). Staging is DMA-contiguous; frag reads
// conflict-free. MODE 0: QKV projection (z = q/k/v, z=2 writes V^T).
// MODE 1: out-projection, split-K x2 over z (z=0 adds bias+residual).
// ---------------------------------------------------------------------------
#define GBM 128
#define GBN 128
#define GBK 64

template<int MODE>
__global__ __launch_bounds__(256, 2)
void gemm_bt(const unsigned short* __restrict__ Aq, const unsigned short* __restrict__ Ak,
             const unsigned short* __restrict__ Av, const unsigned short* __restrict__ Bmat,
             const float* __restrict__ bias0,
             unsigned short* __restrict__ qb, unsigned short* __restrict__ kb,
             unsigned short* __restrict__ vt,
             const float* __restrict__ Res, float* __restrict__ Xout,
             float* __restrict__ Xout2)
{
  __shared__ unsigned short As[GBM * GBK];   // 16 KB, swizzled
  __shared__ unsigned short Bs[GBN * GBK];   // 16 KB, swizzled
  const int tid  = threadIdx.x;
  const int lane = tid & 63;
  const int wave = tid >> 6;
  const int quad = lane >> 4;
  const int c16  = lane & 15;
  const int m0 = blockIdx.y * GBM;
  const int n0 = blockIdx.x * GBN;
  const int z  = blockIdx.z;

  const unsigned short* A;
  const unsigned short* B;
  const float* bias;
  int kbeg, kend;
  if (MODE == 0) {
    A = (z == 0) ? Aq : (z == 1) ? Ak : Av;
    B = Bmat + (size_t)z * E_DIM * E_DIM;
    bias = bias0 + z * E_DIM;
    kbeg = 0; kend = E_DIM;
  } else {
    A = Aq; B = Bmat; bias = bias0;
    kbeg = z * 1024; kend = kbeg + 1024;
  }

  const int srow = lane >> 3;              // 0..7
  const int sc   = (lane & 7) ^ srow;      // XOR-swizzled 16B chunk
  const unsigned short* aG00 = A + (size_t)(m0 + wave * 16 + srow) * E_DIM + kbeg + sc * 8;
  const unsigned short* aG01 = aG00 + (size_t)8 * E_DIM;
  const unsigned short* aG10 = aG00 + (size_t)64 * E_DIM;
  const unsigned short* aG11 = aG00 + (size_t)72 * E_DIM;
  const unsigned short* bG00 = B + (size_t)(n0 + wave * 16 + srow) * E_DIM + kbeg + sc * 8;
  const unsigned short* bG01 = bG00 + (size_t)8 * E_DIM;
  const unsigned short* bG10 = bG00 + (size_t)64 * E_DIM;
  const unsigned short* bG11 = bG00 + (size_t)72 * E_DIM;
  unsigned short* aS00 = &As[wave * 1024];
  unsigned short* aS01 = aS00 + 512;
  unsigned short* aS10 = &As[(wave + 4) * 1024];
  unsigned short* aS11 = aS10 + 512;
  unsigned short* bS00 = &Bs[wave * 1024];
  unsigned short* bS01 = bS00 + 512;
  unsigned short* bS10 = &Bs[(wave + 4) * 1024];
  unsigned short* bS11 = bS10 + 512;

  const int k7 = c16 & 7;
  const int fr0 = (8 * c16 + ((0 * 4 + quad) ^ k7)) * 8;
  const int fr1 = (8 * c16 + ((1 * 4 + quad) ^ k7)) * 8;

  f32x4 acc[4][4];
#pragma unroll
  for (int i = 0; i < 4; i++)
#pragma unroll
    for (int j = 0; j < 4; j++) acc[i][j] = (f32x4){0.f, 0.f, 0.f, 0.f};

  const int wm = (wave >> 1) * 64;
  const int wn = (wave & 1) * 64;
  const int ga = (wm >> 4);
  const int gb = (wn >> 4);

  for (int k0 = kbeg; k0 < kend; k0 += GBK) {
    __syncthreads();
    gl_lds16(aG00, aS00); gl_lds16(aG01, aS01);
    gl_lds16(aG10, aS10); gl_lds16(aG11, aS11);
    gl_lds16(bG00, bS00); gl_lds16(bG01, bS01);
    gl_lds16(bG10, bS10); gl_lds16(bG11, bS11);
    aG00 += GBK; aG01 += GBK; aG10 += GBK; aG11 += GBK;
    bG00 += GBK; bG01 += GBK; bG10 += GBK; bG11 += GBK;
    __syncthreads();

#pragma unroll
    for (int s = 0; s < 2; s++) {
      const int fr = s ? fr1 : fr0;
      bf16x8 af[4], bfr[4];
#pragma unroll
      for (int t = 0; t < 4; t++) {
        af[t]  = *(const bf16x8*)&As[(ga + t) * 1024 + fr];
        bfr[t] = *(const bf16x8*)&Bs[(gb + t) * 1024 + fr];
      }
#pragma unroll
      for (int tm = 0; tm < 4; tm++)
#pragma unroll
        for (int tn = 0; tn < 4; tn++)
          acc[tm][tn] = __builtin_amdgcn_mfma_f32_16x16x32_bf16(af[tm], bfr[tn],
                                                                acc[tm][tn], 0, 0, 0);
    }
  }

  float bv[4];
#pragma unroll
  for (int tn = 0; tn < 4; tn++) bv[tn] = bias[n0 + wn + tn * 16 + c16];

  if (MODE == 1) {
    if (z == 0) {
#pragma unroll
      for (int tm = 0; tm < 4; tm++) {
        int mr = m0 + wm + tm * 16 + quad * 4;
#pragma unroll
        for (int tn = 0; tn < 4; tn++) {
          int n = n0 + wn + tn * 16 + c16;
#pragma unroll
          for (int r = 0; r < 4; r++) {
            size_t idx = (size_t)(mr + r) * E_DIM + n;
            Xout[idx] = acc[tm][tn][r] + bv[tn] + Res[idx];
          }
        }
      }
    } else {
#pragma unroll
      for (int tm = 0; tm < 4; tm++) {
        int mr = m0 + wm + tm * 16 + quad * 4;
#pragma unroll
        for (int tn = 0; tn < 4; tn++) {
          int n = n0 + wn + tn * 16 + c16;
#pragma unroll
          for (int r = 0; r < 4; r++)
            Xout2[(size_t)(mr + r) * E_DIM + n] = acc[tm][tn][r];
        }
      }
    }
  } else if (z < 2) {
    unsigned short* O = (z == 0) ? qb : kb;
#pragma unroll
    for (int tm = 0; tm < 4; tm++) {
      int mr = m0 + wm + tm * 16 + quad * 4;
#pragma unroll
      for (int tn = 0; tn < 4; tn++) {
        int n = n0 + wn + tn * 16 + c16;
#pragma unroll
        for (int r = 0; r < 4; r++)
          O[(size_t)(mr + r) * E_DIM + n] = f2bf(acc[tm][tn][r] + bv[tn]);
      }
    }
  } else {
#pragma unroll
    for (int tm = 0; tm < 4; tm++) {
      int mr = m0 + wm + tm * 16 + quad * 4;
#pragma unroll
      for (int tn = 0; tn < 4; tn++) {
        int n = n0 + wn + tn * 16 + c16;
        uint2 pv;
        pv.x = pack2_bf16(acc[tm][tn][0] + bv[tn], acc[tm][tn][1] + bv[tn]);
        pv.y = pack2_bf16(acc[tm][tn][2] + bv[tn], acc[tm][tn][3] + bv[tn]);
        *(uint2*)(vt + (size_t)n * S_DIM + mr) = pv;
      }
    }
  }
}

// ---------------------------------------------------------------------------
// Flash attention v4 (prefetch after barrier B, operand-swapped QK, fixed-max
// softmax, split-S x2, 40 KB LDS -> 4 blocks/CU).
// ---------------------------------------------------------------------------
__global__ __launch_bounds__(256, 4)
void flash_attn(const unsigned short* __restrict__ qb,
                const unsigned short* __restrict__ kb,
                const unsigned short* __restrict__ vt,
                const float* __restrict__ tb,
                unsigned short* __restrict__ Opart,
                float* __restrict__ lsum)
{
  __shared__ unsigned short Ks[64 * 128];   // 16 KB, swizzled
  __shared__ unsigned short Vs[128 * 64];   // 16 KB, swizzled (V^T)
  __shared__ unsigned short Ps[64 * 64];    //  8 KB, swizzled

  const int tid  = threadIdx.x;
  const int lane = tid & 63;
  const int wave = tid >> 6;
  const int quad = lane >> 4;
  const int c16  = lane & 15;
  const int h     = blockIdx.y;
  const int z     = blockIdx.z;
  const int lrow0 = blockIdx.x * 64 + wave * 16;
  const int sbase = z * 1024;

  bf16x8 qf[4];
#pragma unroll
  for (int kd = 0; kd < 4; kd++)
    qf[kd] = *(const bf16x8*)(qb + (size_t)(lrow0 + c16) * E_DIM + h * D_HEAD
                              + kd * 32 + quad * 8);

  const int krow = tid >> 4;
  const int kc   = tid & 15;
  const int vrow = tid >> 3;
  const int vc   = tid & 7;
  const unsigned short* kg = kb + (size_t)(sbase + krow) * E_DIM + h * D_HEAD + kc * 8;
  const unsigned short* vg = vt + (size_t)(h * D_HEAD + vrow) * S_DIM + sbase + vc * 8;
  const int kslot = (kc ^ krow) * 8;
  const int vslot = (vc ^ (vrow & 7)) * 8;
  const float* tbh = tb + (size_t)h * S_DIM + sbase;

  f32x4 of[8];
#pragma unroll
  for (int i = 0; i < 8; i++) of[i] = (f32x4){0.f, 0.f, 0.f, 0.f};
  float li4[4] = {0.f, 0.f, 0.f, 0.f};

  bf16x8 kreg[4], vreg[4];
#pragma unroll
  for (int i = 0; i < 4; i++) kreg[i] = *(const bf16x8*)(kg + (size_t)i * 16 * E_DIM);
#pragma unroll
  for (int i = 0; i < 4; i++) vreg[i] = *(const bf16x8*)(vg + (size_t)i * 32 * S_DIM);

  const int prow = (wave * 16 + c16) * 64;
  const int k7   = c16 & 7;

  for (int ch = 0; ch < 16; ch++) {
    __syncthreads();   // A: drains prefetch (issued a full compute phase ago)
#pragma unroll
    for (int i = 0; i < 4; i++)
      *(bf16x8*)&Ks[(krow + 16 * i) * 128 + kslot] = kreg[i];
#pragma unroll
    for (int i = 0; i < 4; i++)
      *(bf16x8*)&Vs[(vrow + 32 * i) * 64 + vslot] = vreg[i];
    __syncthreads();   // B: vmcnt already 0 -> cheap

    if (ch < 15) {     // prefetch next chunk: stays in flight through compute
      const unsigned short* kg2 = kg + (size_t)(ch + 1) * 64 * E_DIM;
      const unsigned short* vg2 = vg + (ch + 1) * 64;
#pragma unroll
      for (int i = 0; i < 4; i++) kreg[i] = *(const bf16x8*)(kg2 + (size_t)i * 16 * E_DIM);
#pragma unroll
      for (int i = 0; i < 4; i++) vreg[i] = *(const bf16x8*)(vg2 + (size_t)i * 32 * S_DIM);
    }

    float4 bb[4];
#pragma unroll
    for (int tn = 0; tn < 4; tn++)
      bb[tn] = *(const float4*)(tbh + ch * 64 + tn * 16 + quad * 4);

    // S^T = K * Q^T: sc[tn][r] = S[l=c16][s = tn*16 + quad*4 + r]
    f32x4 sc[4];
#pragma unroll
    for (int tn = 0; tn < 4; tn++) sc[tn] = (f32x4){0.f, 0.f, 0.f, 0.f};
#pragma unroll
    for (int tn = 0; tn < 4; tn++)
#pragma unroll
      for (int kd = 0; kd < 4; kd++) {
        bf16x8 kf = *(const bf16x8*)&Ks[(tn * 16 + c16) * 128
                                        + (((kd * 4 + quad) ^ c16) << 3)];
        sc[tn] = __builtin_amdgcn_mfma_f32_16x16x32_bf16(kf, qf[kd], sc[tn], 0, 0, 0);
      }

#pragma unroll
    for (int tn = 0; tn < 4; tn++) {
      float p0 = exp2f(fmaf(sc[tn][0], FA_C1, bb[tn].x));
      float p1 = exp2f(fmaf(sc[tn][1], FA_C1, bb[tn].y));
      float p2 = exp2f(fmaf(sc[tn][2], FA_C1, bb[tn].z));
      float p3 = exp2f(fmaf(sc[tn][3], FA_C1, bb[tn].w));
      li4[tn] += (p0 + p1) + (p2 + p3);
      uint2 pv;
      pv.x = pack2_bf16(p0, p1);
      pv.y = pack2_bf16(p2, p3);
      int p8 = (((tn * 2 + (quad >> 1)) ^ k7) << 1) | (quad & 1);
      *(uint2*)&Ps[prow + p8 * 4] = pv;
    }

#pragma unroll
    for (int ks = 0; ks < 2; ks++) {
      int po = ((ks * 4 + quad) ^ k7) << 3;
      bf16x8 ap = *(const bf16x8*)&Ps[prow + po];
#pragma unroll
      for (int td = 0; td < 8; td++) {
        bf16x8 vf = *(const bf16x8*)&Vs[(td * 16 + c16) * 64 + po];
        of[td] = __builtin_amdgcn_mfma_f32_16x16x32_bf16(ap, vf, of[td], 0, 0, 0);
      }
    }
  }

  float lt = (li4[0] + li4[1]) + (li4[2] + li4[3]);
  lt += __shfl_xor(lt, 16, 64);
  lt += __shfl_xor(lt, 32, 64);
  if (quad == 0)
    lsum[(size_t)z * 32768 + (size_t)h * 2048 + lrow0 + c16] = lt;

#pragma unroll
  for (int r = 0; r < 4; r++) {
    size_t lrow = lrow0 + quad * 4 + r;
#pragma unroll
    for (int td = 0; td < 8; td++)
      Opart[((size_t)z * 2048 + lrow) * 2048 + h * D_HEAD + td * 16 + c16] =
          f2bf(of[td][r]);
  }
}

// ---------------------------------------------------------------------------
// combine: ctx = (O0 + O1) / (l0 + l1), bf16 in/out.
// ---------------------------------------------------------------------------
__global__ __launch_bounds__(256)
void combine_kernel(const unsigned short* __restrict__ Opart,
                    const float* __restrict__ lsum,
                    unsigned short* __restrict__ ctx)
{
  size_t i = ((size_t)blockIdx.x * 256 + threadIdx.x) * 8;
  int l = (int)(i >> 11);
  int e = (int)(i & 2047);
  int h = e >> 7;
  float inv = 1.0f / (lsum[h * 2048 + l] + lsum[32768 + h * 2048 + l]);
  uint4 a = *(const uint4*)(Opart + i);
  uint4 b = *(const uint4*)(Opart + 4194304 + i);
  uint4 o;
  o.x = pack2_bf16((bflo(a.x) + bflo(b.x)) * inv, (bfhi(a.x) + bfhi(b.x)) * inv);
  o.y = pack2_bf16((bflo(a.y) + bflo(b.y)) * inv, (bfhi(a.y) + bfhi(b.y)) * inv);
  o.z = pack2_bf16((bflo(a.z) + bflo(b.z)) * inv, (bfhi(a.z) + bfhi(b.z)) * inv);
  o.w = pack2_bf16((bflo(a.w) + bflo(b.w)) * inv, (bfhi(a.w) + bfhi(b.w)) * inv);
  *(uint4*)(ctx + i) = o;
}

// ---------------------------------------------------------------------------
// LayerNorm over rows of (xb0 + xb1) (split-K partials), eps=1e-5
// ---------------------------------------------------------------------------
__global__ __launch_bounds__(256)
void layernorm_kernel(const float* __restrict__ x0, const float* __restrict__ x1,
                      const float* __restrict__ g, const float* __restrict__ b,
                      float* __restrict__ out)
{
  const int row = blockIdx.x;
  const int tid = threadIdx.x;
  const int lane = tid & 63, wave = tid >> 6;
  const float* xr0 = x0 + (size_t)row * E_DIM;
  const float* xr1 = x1 + (size_t)row * E_DIM;
  float4 a0 = *(const float4*)(xr0 + tid * 4);
  float4 a1 = *(const float4*)(xr0 + 1024 + tid * 4);
  float4 c0 = *(const float4*)(xr1 + tid * 4);
  float4 c1 = *(const float4*)(xr1 + 1024 + tid * 4);
  float4 v0 = {a0.x + c0.x, a0.y + c0.y, a0.z + c0.z, a0.w + c0.w};
  float4 v1 = {a1.x + c1.x, a1.y + c1.y, a1.z + c1.z, a1.w + c1.w};
  float s  = v0.x + v0.y + v0.z + v0.w + v1.x + v1.y + v1.z + v1.w;
  float ss = v0.x*v0.x + v0.y*v0.y + v0.z*v0.z + v0.w*v0.w
           + v1.x*v1.x + v1.y*v1.y + v1.z*v1.z + v1.w*v1.w;
#pragma unroll
  for (int d = 1; d < 64; d <<= 1) {
    s  += __shfl_xor(s, d, 64);
    ss += __shfl_xor(ss, d, 64);
  }
  __shared__ float red[8];
  if (lane == 0) { red[wave] = s; red[wave + 4] = ss; }
  __syncthreads();
  s  = red[0] + red[1] + red[2] + red[3];
  ss = red[4] + red[5] + red[6] + red[7];
  float mu   = s * (1.f / E_DIM);
  float var  = ss * (1.f / E_DIM) - mu * mu;
  float rstd = rsqrtf(var + 1e-5f);

  float4 g0 = *(const float4*)(g + tid * 4);
  float4 b0 = *(const float4*)(b + tid * 4);
  float4 g1 = *(const float4*)(g + 1024 + tid * 4);
  float4 b1 = *(const float4*)(b + 1024 + tid * 4);
  float4 o0, o1;
  o0.x = (v0.x - mu) * rstd * g0.x + b0.x;
  o0.y = (v0.y - mu) * rstd * g0.y + b0.y;
  o0.z = (v0.z - mu) * rstd * g0.z + b0.z;
  o0.w = (v0.w - mu) * rstd * g0.w + b0.w;
  o1.x = (v1.x - mu) * rstd * g1.x + b1.x;
  o1.y = (v1.y - mu) * rstd * g1.y + b1.y;
  o1.z = (v1.z - mu) * rstd * g1.z + b1.z;
  o1.w = (v1.w - mu) * rstd * g1.w + b1.w;
  *(float4*)(out + (size_t)row * E_DIM + tid * 4) = o0;
  *(float4*)(out + (size_t)row * E_DIM + 1024 + tid * 4) = o1;
}

extern "C" void kernel_launch(void* const* d_in, const int* in_sizes, int n_in,
                              void* d_out, int out_size, void* d_ws, size_t ws_size,
                              hipStream_t stream) {
  const float* query     = (const float*)d_in[0];
  const float* key       = (const float*)d_in[1];
  const float* value     = (const float*)d_in[2];
  const float* time_emb  = (const float*)d_in[3];
  const float* in_proj_w = (const float*)d_in[4];
  const float* in_proj_b = (const float*)d_in[5];
  const float* out_w     = (const float*)d_in[6];
  const float* out_b     = (const float*)d_in[7];
  const float* tp_w      = (const float*)d_in[8];
  const float* tp_b      = (const float*)d_in[9];
  const float* ln_g      = (const float*)d_in[10];
  const float* ln_b      = (const float*)d_in[11];

  char* ws = (char*)d_ws;
  unsigned short* qa   = (unsigned short*)(ws + 0);         //  8 MB (dead after gemm0)
  unsigned short* ka   = (unsigned short*)(ws + 8388608);   //  8 MB (dead after gemm0)
  unsigned short* va   = (unsigned short*)(ws + 16777216);  //  8 MB (dead after gemm0)
  unsigned short* wqkv = (unsigned short*)(ws + 25165824);  // 24 MB (dead after gemm0)
  unsigned short* wo   = (unsigned short*)(ws + 50331648);  //  8 MB (until gemm1)
  unsigned short* qb   = (unsigned short*)(ws + 58720256);  //  8 MB (until flash)
  unsigned short* kb   = (unsigned short*)(ws + 67108864);  //  8 MB (until flash)
  unsigned short* vt   = (unsigned short*)(ws + 75497472);  //  8 MB (until flash)
  float*          tb   = (float*)(ws + 83886080);           // 128 KB (until flash)
  // aliases (serial stream; lifetimes disjoint):
  unsigned short* Opart = (unsigned short*)(ws + 0);        // 16 MB over qa/ka (dead)
  float*          lsum  = (float*)(ws + 16777216);          // 256 KB over va (dead)
  unsigned short* ctx   = (unsigned short*)(ws + 33554432); //  8 MB over wqkv (dead)
  float*          xb0   = (float*)(ws + 0);                 // 16 MB over Opart (dead)
  float*          xb1   = (float*)(ws + 16777216);          // 16 MB over lsum (dead)

  // 1) fp32 -> bf16 conversions (high-MLP version)
  convert_bf16<<<3584, 256, 0, stream>>>(query, key, value, in_proj_w, out_w,
                                         qa, ka, va, wqkv, wo);
  // 2) per-head time bias (pre-scaled by log2e, shift folded in)
  time_bias_kernel<<<512, 256, 0, stream>>>(time_emb, tp_w, tp_b, tb);
  // 3) QKV projection (z selects q/k/v; V stored transposed)
  gemm_bt<0><<<dim3(16, 16, 3), 256, 0, stream>>>(qa, ka, va, wqkv, in_proj_b,
                                                  qb, kb, vt, nullptr, nullptr,
                                                  nullptr);
  // 4) flash attention, split-S x2 -> unnormalized bf16 partials
  flash_attn<<<dim3(32, 16, 2), 256, 0, stream>>>(qb, kb, vt, tb, Opart, lsum);
  // 5) combine partials -> ctx (bf16)
  combine_kernel<<<2048, 256, 0, stream>>>(Opart, lsum, ctx);
  // 6) out projection split-K x2 (+ bias + residual on z=0) -> xb0, xb1
  gemm_bt<1><<<dim3(16, 16, 2), 256, 0, stream>>>(ctx, nullptr, nullptr, wo,
                                                  out_b, nullptr, nullptr, nullptr,
                                                  query, xb0, xb1);
  // 7) LayerNorm over xb0+xb1 -> d_out
  layernorm_kernel<<<2048, 256, 0, stream>>>(xb0, xb1, ln_g, ln_b, (float*)d_out);
}